// Round 3
// baseline (261.047 us; speedup 1.0000x reference)
//
#include <hip/hip_runtime.h>
#include <math.h>

// Problem constants (reference shapes are fixed)
constexpr int Bc = 8, Cc = 64, Hc = 256, Wc = 256, Sc = 4;
constexpr int NPATCH = Bc * (Hc / Sc) * (Wc / Sc);  // 32768
constexpr int TP = 8;        // patches per block (32 contiguous columns)
constexpr int CP = 132;      // T pitch per channel, floats: 8 patches*16 px + 4 pad (16B aligned)
constexpr int MP = 65;       // cmbuf pitch (bank-staggered)
constexpr int GP = 20;       // g1buf pitch (16B aligned, staggered)

__device__ __forceinline__ float sigmoidf_(float v) {
    return 1.0f / (1.0f + __expf(-v));
}

// Block = 256 threads (4 waves) handles 8 adjacent patches (one b, ph, 32-col strip).
// T holds the ORIGINAL x tile (read-only); all three gates are composed at stage-out:
//   out = x * m[c] * g1[t] * g2[p]
// Patch gate g2 derives algebraically from per-pixel results (g1>0):
//   patch_sum = sum_t g1[t]*s[t],  patch_max = max_t g1[t]*mxp[t]
// so there is no second pass over the tile and no write-back to T.
__global__ __launch_bounds__(256, 3)
void ciam_kernel(const float* __restrict__ x,
                 const float* __restrict__ fc_w,
                 const float* __restrict__ fc_b,
                 const float* __restrict__ c1w,
                 const float* __restrict__ c1b,
                 const float* __restrict__ c2w,
                 const float* __restrict__ c2b,
                 float* __restrict__ out)
{
    __shared__ float T[64 * CP];       // 33792 B  x tile, layout [c][p][t], t = r*4+j
    __shared__ float fcw[64 * 65];     // 16640 B  fc_w, pitch 65 (conflict-free row reads)
    __shared__ float cmbuf[TP * MP];   //  2080 B  per-patch: channel-max, then m-gate
    __shared__ float g1buf[TP * GP];   //   640 B  per-patch pixel gates
    __shared__ float g2buf[TP];        //    32 B  per-patch gate
    // total 53184 B -> 3 blocks/CU

    const int tid = threadIdx.x;
    const int gid = blockIdx.x;
    const int b    = gid >> 9;
    const int rem  = gid & 511;
    const int ph   = rem >> 3;
    const int col0 = (rem & 7) * 32;

    // ---- Stage fc_w (64x64) into LDS, coalesced float4 reads ----
    #pragma unroll
    for (int i = 0; i < 4; ++i) {
        int u   = i * 256 + tid;
        int row = u >> 4;
        int jf  = (u & 15) << 2;
        const float4 wv = *reinterpret_cast<const float4*>(fc_w + row * 64 + jf);
        float* fd = &fcw[row * 65 + jf];
        fd[0] = wv.x; fd[1] = wv.y; fd[2] = wv.z; fd[3] = wv.w;
    }

    // ---- Stage tile: one float4 = (channel c, patch p, row r) -> T[c][p][r*4..r*4+3] ----
    #pragma unroll
    for (int i = 0; i < 8; ++i) {
        int u   = i * 256 + tid;
        int seg = u >> 3;           // (c, r)
        int c_  = seg >> 2;
        int r_  = seg & 3;
        int p_  = u & 7;
        const float4 val = *reinterpret_cast<const float4*>(
            x + (((size_t)(b * Cc + c_) * Hc + (ph * Sc + r_)) * Wc + col0 + 4 * p_));
        *reinterpret_cast<float4*>(&T[c_ * CP + p_ * 16 + r_ * 4]) = val;
    }

    const float w10 = c1w[0], w11 = c1w[1], b1 = c1b[0];
    const float w20 = c2w[0], w21 = c2w[1], b2 = c2b[0];

    __syncthreads();

    const int wave = tid >> 6;
    const int lane = tid & 63;
    const int p0   = wave * 2;      // this wave's two patches

    // ---- Per-channel max over 16 pixels (lane = channel), both patches ----
    #pragma unroll
    for (int pi = 0; pi < 2; ++pi) {
        const float* tp = &T[lane * CP + (p0 + pi) * 16];
        float4 a = *reinterpret_cast<const float4*>(tp + 0);
        float4 bq = *reinterpret_cast<const float4*>(tp + 4);
        float4 cq = *reinterpret_cast<const float4*>(tp + 8);
        float4 dq = *reinterpret_cast<const float4*>(tp + 12);
        float mv = fmaxf(fmaxf(fmaxf(a.x, a.y), fmaxf(a.z, a.w)),
                         fmaxf(fmaxf(bq.x, bq.y), fmaxf(bq.z, bq.w)));
        mv = fmaxf(mv, fmaxf(fmaxf(cq.x, cq.y), fmaxf(cq.z, cq.w)));
        mv = fmaxf(mv, fmaxf(fmaxf(dq.x, dq.y), fmaxf(dq.z, dq.w)));
        cmbuf[(p0 + pi) * MP + lane] = mv;
    }
    __syncthreads();

    // ---- FC + sigmoid -> m gate; overwrite cmbuf with m ----
    {
        const float bias = fc_b[lane];
        float a0 = bias, a1 = bias;
        const float* m0p = &cmbuf[p0 * MP];
        const float* m1p = &cmbuf[(p0 + 1) * MP];
        const float* wr  = &fcw[lane * 65];
        #pragma unroll 16
        for (int k = 0; k < 64; ++k) {
            float wv = wr[k];
            a0 = fmaf(wv, m0p[k], a0);
            a1 = fmaf(wv, m1p[k], a1);
        }
        float m0 = sigmoidf_(a0), m1 = sigmoidf_(a1);
        cmbuf[p0 * MP + lane]       = m0;   // safe: all reads above precede (data dep)
        cmbuf[(p0 + 1) * MP + lane] = m1;
    }
    __syncthreads();

    // ---- Per-pixel channel mean/max + pixel gate + patch gate (no second tile pass) ----
    {
        const int q = lane >> 4, t = lane & 15;   // 4 channel-quarters x 16 pixels
        #pragma unroll
        for (int pi = 0; pi < 2; ++pi) {
            const int p = p0 + pi;
            const float* tp = &T[(q * 16) * CP + p * 16 + t];
            const float* mp = &cmbuf[p * MP + q * 16];
            float s = 0.f, mx = -3.4e38f;
            #pragma unroll
            for (int i = 0; i < 16; ++i) {
                float u = tp[i * CP] * mp[i];     // m-scaled value
                s += u;
                mx = fmaxf(mx, u);
            }
            s  += __shfl_xor(s, 16);
            s  += __shfl_xor(s, 32);
            mx  = fmaxf(mx, __shfl_xor(mx, 16));
            mx  = fmaxf(mx, __shfl_xor(mx, 32));
            const float g1 = sigmoidf_(w10 * (s * (1.f / 64.f)) + w11 * mx + b1);
            // patch stats from per-pixel results (g1 > 0)
            float pa = g1 * s, pm = g1 * mx;
            #pragma unroll
            for (int off = 1; off <= 8; off <<= 1) {
                pa += __shfl_xor(pa, off);
                pm  = fmaxf(pm, __shfl_xor(pm, off));
            }
            const float g2 = sigmoidf_(w20 * (pa * (1.f / 1024.f)) + w21 * pm + b2);
            if (lane < 16) g1buf[p * GP + lane] = g1;
            if (lane == 0) g2buf[p] = g2;
        }
    }
    __syncthreads();

    // ---- Stage-out: read original x from T, compose all gates, coalesced stores ----
    #pragma unroll
    for (int i = 0; i < 8; ++i) {
        int u   = i * 256 + tid;
        int seg = u >> 3;
        int c_  = seg >> 2;
        int r_  = seg & 3;
        int p_  = u & 7;
        const float4 xv = *reinterpret_cast<const float4*>(&T[c_ * CP + p_ * 16 + r_ * 4]);
        const float ms = cmbuf[p_ * MP + c_] * g2buf[p_];
        const float4 g1v = *reinterpret_cast<const float4*>(&g1buf[p_ * GP + r_ * 4]);
        float4 o;
        o.x = xv.x * ms * g1v.x;
        o.y = xv.y * ms * g1v.y;
        o.z = xv.z * ms * g1v.z;
        o.w = xv.w * ms * g1v.w;
        *reinterpret_cast<float4*>(
            out + (((size_t)(b * Cc + c_) * Hc + (ph * Sc + r_)) * Wc + col0 + 4 * p_)) = o;
    }
}

extern "C" void kernel_launch(void* const* d_in, const int* in_sizes, int n_in,
                              void* d_out, int out_size, void* d_ws, size_t ws_size,
                              hipStream_t stream) {
    const float* x    = (const float*)d_in[0];
    const float* fc_w = (const float*)d_in[1];
    const float* fc_b = (const float*)d_in[2];
    const float* c1w  = (const float*)d_in[3];
    const float* c1b  = (const float*)d_in[4];
    const float* c2w  = (const float*)d_in[5];
    const float* c2b  = (const float*)d_in[6];
    // d_in[7] = size (int, ==4) -- shapes hardcoded to the reference.

    float* out = (float*)d_out;
    ciam_kernel<<<NPATCH / TP, 256, 0, stream>>>(x, fc_w, fc_b, c1w, c1b, c2w, c2b, out);
}